// Round 13
// baseline (226.301 us; speedup 1.0000x reference)
//
#include <hip/hip_runtime.h>
#include <math.h>

#define N_ENT 40000
#define N_NODES 40500
#define EMB 256
#define N_EDGES 648000
#define BATCH 1024
#define BN_EPS 1e-5f
#define SCAN_NB 40   // ceil(N_NODES/1024)

typedef __attribute__((ext_vector_type(8))) _Float16 half8;
typedef __attribute__((ext_vector_type(4))) _Float16 half4v;
typedef __attribute__((ext_vector_type(4))) float f32x4;

__device__ __forceinline__ void gl_lds16(const void* g, void* l) {
    __builtin_amdgcn_global_load_lds(
        (const __attribute__((address_space(1))) void*)g,
        (__attribute__((address_space(3))) void*)l, 16, 0, 0);
}

// ---------------------------------------------------------------- CSR: histogram
__global__ void hist_k(const int* __restrict__ src, int* __restrict__ cnt) {
    int e = blockIdx.x * 256 + threadIdx.x;
    if (e < N_EDGES) atomicAdd(&cnt[src[e]], 1);
}

// ---- fused: blocks 0..39 = per-block scan of cnt; blocks 40..103 = hamilton fp16
__global__ __launch_bounds__(1024) void scanham(const int* __restrict__ cnt,
                                                int* __restrict__ row_start,
                                                int* __restrict__ bsum,
                                                const float* __restrict__ qw,
                                                _Float16* __restrict__ Hth) {
    const int t = threadIdx.x;
    if (blockIdx.x < SCAN_NB) {
        __shared__ int wsum[16];
        const int lane = t & 63, wid = t >> 6;
        int idx = blockIdx.x * 1024 + t;
        int v = (idx < N_NODES) ? cnt[idx] : 0;
        int incl = v;
        #pragma unroll
        for (int off = 1; off < 64; off <<= 1) {
            int u = __shfl_up(incl, off);
            if (lane >= off) incl += u;
        }
        if (lane == 63) wsum[wid] = incl;
        __syncthreads();
        if (t < 16) {
            int wv = wsum[t];
            #pragma unroll
            for (int off = 1; off < 16; off <<= 1) {
                int u = __shfl_up(wv, off);
                if (t >= off) wv += u;
            }
            wsum[t] = wv;
        }
        __syncthreads();
        int woff = (wid > 0) ? wsum[wid - 1] : 0;
        incl += woff;
        if (idx < N_NODES) row_start[idx] = incl - v;   // block-local exclusive
        if (t == 1023) bsum[blockIdx.x] = incl;
    } else {
        int idx = (blockIdx.x - SCAN_NB) * 1024 + t;    // 65536
        int o = idx >> 8, i = idx & 255;
        int p = i >> 6, i0 = i & 63;
        int q = o >> 6, o0 = o & 63;
        const int   ctab[16] = {0,1,2,3, 1,0,3,2, 2,3,0,1, 3,2,1,0};
        const float stab[16] = {1.f,1.f,1.f,1.f, -1.f,1.f,1.f,-1.f, -1.f,-1.f,1.f,1.f, -1.f,1.f,-1.f,1.f};
        Hth[idx] = (_Float16)(stab[p*4+q] * qw[i0*EMB + ctab[p*4+q]*64 + o0]);
    }
}

// ---- scan_add: each block redoes the 40-element top scan, adds offset,
// ---- writes row_start + cursor (+ total tail)
__global__ __launch_bounds__(1024) void scan_add(int* __restrict__ row_start,
                                                 int* __restrict__ cursor,
                                                 const int* __restrict__ bsum) {
    __shared__ int off_s, tot_s;
    const int t = threadIdx.x;
    if (t < 64) {
        int v = (t < SCAN_NB) ? bsum[t] : 0;
        int incl = v;
        #pragma unroll
        for (int off = 1; off < 64; off <<= 1) {
            int u = __shfl_up(incl, off);
            if (t >= off) incl += u;
        }
        int off = (blockIdx.x == 0) ? 0 : __shfl(incl, (int)blockIdx.x - 1);
        int tot = __shfl(incl, SCAN_NB - 1);
        if (t == 0) { off_s = off; tot_s = tot; }
    }
    __syncthreads();
    int idx = blockIdx.x * 1024 + t;
    if (idx < N_NODES) {
        int v = row_start[idx] + off_s;
        row_start[idx] = v;
        cursor[idx] = v;
    }
    if (idx == N_NODES) row_start[N_NODES] = tot_s;
}

// ---- fused: blocks 0..632 = support GEMM (fp16 MFMA); blocks 633.. = place_edges
__global__ __launch_bounds__(256) void support_place(const float* __restrict__ emb,
                                                     const _Float16* __restrict__ Hth,
                                                     _Float16* __restrict__ Ch,
                                                     const int* __restrict__ esrc,
                                                     const int* __restrict__ edst,
                                                     const float* __restrict__ evalv,
                                                     int* __restrict__ cursor,
                                                     int2* __restrict__ edge_s) {
    if (blockIdx.x >= 633) {
        int e = (blockIdx.x - 633) * 256 + threadIdx.x;
        if (e < N_EDGES) {
            int pos = atomicAdd(&cursor[esrc[e]], 1);
            edge_s[pos] = make_int2(edst[e], __float_as_int(evalv[e]));
        }
        return;
    }
    const int wid  = threadIdx.x >> 6;
    const int lane = threadIdx.x & 63;
    const int wr = wid >> 1, wc = wid & 1;
    const int row0 = blockIdx.x * 64 + wr * 32;
    const int col0 = wc * 128;
    const int fr = lane & 15;
    const int kg = lane >> 4;
    f32x4 acc[2][8] = {};
    for (int kb = 0; kb < 8; ++kb) {
        const int koff = kb * 32 + kg * 8;
        half8 a[2];
        #pragma unroll
        for (int i = 0; i < 2; ++i) {
            int r = row0 + i * 16 + fr;
            if (r > N_NODES - 1) r = N_NODES - 1;
            const float* src = emb + (size_t)r * EMB + koff;
            float4 va = *(const float4*)(src);
            float4 vb = *(const float4*)(src + 4);
            a[i][0] = (_Float16)va.x; a[i][1] = (_Float16)va.y;
            a[i][2] = (_Float16)va.z; a[i][3] = (_Float16)va.w;
            a[i][4] = (_Float16)vb.x; a[i][5] = (_Float16)vb.y;
            a[i][6] = (_Float16)vb.z; a[i][7] = (_Float16)vb.w;
        }
        half8 b[8];
        #pragma unroll
        for (int j = 0; j < 8; ++j)
            b[j] = *(const half8*)(Hth + (size_t)(col0 + j * 16 + fr) * EMB + koff);
        #pragma unroll
        for (int i = 0; i < 2; ++i)
            #pragma unroll
            for (int j = 0; j < 8; ++j)
                acc[i][j] = __builtin_amdgcn_mfma_f32_16x16x32_f16(a[i], b[j], acc[i][j], 0, 0, 0);
    }
    #pragma unroll
    for (int i = 0; i < 2; ++i) {
        int rbase = row0 + i * 16 + (lane >> 4) * 4;
        #pragma unroll
        for (int j = 0; j < 8; ++j) {
            int c = col0 + j * 16 + (lane & 15);
            #pragma unroll
            for (int r = 0; r < 4; ++r) {
                if (rbase + r < N_NODES)
                    Ch[(size_t)(rbase + r) * EMB + c] = (_Float16)acc[i][j][r];
            }
        }
    }
}

// -------- Xh[row] = tanh( sum val*support_h[dst] ), int2 edges, 4-wide unroll
__global__ __launch_bounds__(256) void spmm_tanh(const int* __restrict__ row_start,
                                                 const int2* __restrict__ edge_s,
                                                 const _Float16* __restrict__ support_h,
                                                 _Float16* __restrict__ Xh) {
    int row = blockIdx.x * 4 + (threadIdx.x >> 6);
    if (row >= N_NODES) return;
    int lane = threadIdx.x & 63;
    int beg = row_start[row], end = row_start[row + 1];
    float4 acc = make_float4(0.f, 0.f, 0.f, 0.f);
    int i = beg;
    for (; i + 3 < end; i += 4) {
        int2 e0 = edge_s[i], e1 = edge_s[i+1], e2 = edge_s[i+2], e3 = edge_s[i+3];
        half4v x0 = *(const half4v*)(support_h + (size_t)e0.x * EMB + lane * 4);
        half4v x1 = *(const half4v*)(support_h + (size_t)e1.x * EMB + lane * 4);
        half4v x2 = *(const half4v*)(support_h + (size_t)e2.x * EMB + lane * 4);
        half4v x3 = *(const half4v*)(support_h + (size_t)e3.x * EMB + lane * 4);
        float v0 = __int_as_float(e0.y), v1 = __int_as_float(e1.y);
        float v2 = __int_as_float(e2.y), v3 = __int_as_float(e3.y);
        acc.x = fmaf(v0, (float)x0[0], acc.x); acc.y = fmaf(v0, (float)x0[1], acc.y);
        acc.z = fmaf(v0, (float)x0[2], acc.z); acc.w = fmaf(v0, (float)x0[3], acc.w);
        acc.x = fmaf(v1, (float)x1[0], acc.x); acc.y = fmaf(v1, (float)x1[1], acc.y);
        acc.z = fmaf(v1, (float)x1[2], acc.z); acc.w = fmaf(v1, (float)x1[3], acc.w);
        acc.x = fmaf(v2, (float)x2[0], acc.x); acc.y = fmaf(v2, (float)x2[1], acc.y);
        acc.z = fmaf(v2, (float)x2[2], acc.z); acc.w = fmaf(v2, (float)x2[3], acc.w);
        acc.x = fmaf(v3, (float)x3[0], acc.x); acc.y = fmaf(v3, (float)x3[1], acc.y);
        acc.z = fmaf(v3, (float)x3[2], acc.z); acc.w = fmaf(v3, (float)x3[3], acc.w);
    }
    for (; i < end; ++i) {
        int2 e = edge_s[i];
        float v = __int_as_float(e.y);
        half4v x = *(const half4v*)(support_h + (size_t)e.x * EMB + lane * 4);
        acc.x = fmaf(v, (float)x[0], acc.x);
        acc.y = fmaf(v, (float)x[1], acc.y);
        acc.z = fmaf(v, (float)x[2], acc.z);
        acc.w = fmaf(v, (float)x[3], acc.w);
    }
    half4v o;
    o[0] = (_Float16)tanhf(acc.x); o[1] = (_Float16)tanhf(acc.y);
    o[2] = (_Float16)tanhf(acc.z); o[3] = (_Float16)tanhf(acc.w);
    *(half4v*)(Xh + (size_t)row * EMB + lane * 4) = o;
}

// ---- fused hr + batchnorm (stats + apply) -> fp16; one block per feature
__global__ __launch_bounds__(256) void bn_fused(const _Float16* __restrict__ Xh,
                                                const int* __restrict__ e1,
                                                const int* __restrict__ ri,
                                                const float* __restrict__ gamma,
                                                const float* __restrict__ beta,
                                                _Float16* __restrict__ hr_h) {
    const int f = blockIdx.x, t = threadIdx.x;
    float v[4];
    float s = 0.f, sq = 0.f;
    #pragma unroll
    for (int k = 0; k < 4; ++k) {
        int b = t + k * 256;
        float h = (float)Xh[(size_t)e1[b] * EMB + f];
        float r = (float)Xh[((size_t)ri[b] + N_ENT) * EMB + f];
        v[k] = h * r;
        s += v[k]; sq += v[k] * v[k];
    }
    #pragma unroll
    for (int off = 32; off > 0; off >>= 1) {
        s  += __shfl_down(s, off);
        sq += __shfl_down(sq, off);
    }
    __shared__ float ss[4], sqs[4], mv[2];
    int w = t >> 6;
    if ((t & 63) == 0) { ss[w] = s; sqs[w] = sq; }
    __syncthreads();
    if (t == 0) {
        s  = ss[0] + ss[1] + ss[2] + ss[3];
        sq = sqs[0] + sqs[1] + sqs[2] + sqs[3];
        float m = s * (1.f / BATCH);
        mv[0] = m;
        mv[1] = sq * (1.f / BATCH) - m * m;
    }
    __syncthreads();
    float mean = mv[0];
    float inv = rsqrtf(mv[1] + BN_EPS) * gamma[f];
    float bet = beta[f];
    #pragma unroll
    for (int k = 0; k < 4; ++k) {
        int b = t + k * 256;
        hr_h[(size_t)b * EMB + f] = (_Float16)((v[k] - mean) * inv + bet);
    }
}

// ------------- out = sigmoid(hr_h @ Xh[:N_ENT]^T), fp16 MFMA LDS GEMM
// v4: block 128(M) x 128(N), BK=32, 4 waves 2x2 (wave 64x64 = 4x4 frags,
// 16 MFMA/step/wave). A LDS [128][32] = bytes 0..8191, B LDS [128][32] =
// bytes 8192..16383 (chunk ch stages at smem + ch*1024, ch = 0..15).
// Epilogue in two 64-row passes through Ep[64][132].
__global__ __launch_bounds__(256) void score_v4(const _Float16* __restrict__ hr_h,
                                                const _Float16* __restrict__ Xh,
                                                float* __restrict__ out) {
    __shared__ char smem[64 * 132 * 4];       // 33.8 KB (K-loop uses first 16 KB)
    _Float16* As = (_Float16*)smem;           // [128][32] bytes 0..8191
    _Float16* Bs = As + 4096;                 // [128][32] bytes 8192..16383
    float* Ep = (float*)smem;                 // [64][132] (epilogue)

    const int tid  = threadIdx.x;
    const int wid  = tid >> 6;
    const int lane = tid & 63;
    const int wr = wid >> 1, wc = wid & 1;
    const int row0 = blockIdx.x * 128;        // M block (8)
    const int col0 = blockIdx.y * 128;        // N block (313)
    const int fr = lane & 15;
    const int kg = lane >> 4;
    const int lrow = lane >> 2;
    const int lchk = (lane & 3) * 8;

    f32x4 acc[4][4] = {};

    for (int kb = 0; kb < 8; ++kb) {
        const int koff = kb * 32;
        // ---- stage A (chunks 0-7) + B (chunks 8-15); 4 chunks per wave
        #pragma unroll
        for (int c = 0; c < 4; ++c) {
            int ch = wid * 4 + c;                      // 0..15
            if (ch < 8) {
                int lr = ch * 16 + lrow;               // 0..127
                const _Float16* srcA = hr_h + (size_t)(row0 + lr) * EMB + koff + lchk;
                gl_lds16(srcA, smem + ch * 1024);
            } else {
                int br = (ch - 8) * 16 + lrow;         // 0..127
                int gc = col0 + br;
                if (gc > N_ENT - 1) gc = N_ENT - 1;
                const _Float16* srcB = Xh + (size_t)gc * EMB + koff + lchk;
                gl_lds16(srcB, smem + ch * 1024);      // bytes 8192..16383
            }
        }
        __syncthreads();
        // ---- fragments from LDS + MFMA (4x4)
        half8 a_[4], b_[4];
        #pragma unroll
        for (int i = 0; i < 4; ++i) {
            int r = wr * 64 + i * 16 + fr;
            a_[i] = *(const half8*)&As[r * 32 + kg * 8];
        }
        #pragma unroll
        for (int j = 0; j < 4; ++j) {
            int r = wc * 64 + j * 16 + fr;
            b_[j] = *(const half8*)&Bs[r * 32 + kg * 8];
        }
        #pragma unroll
        for (int i = 0; i < 4; ++i)
            #pragma unroll
            for (int j = 0; j < 4; ++j)
                acc[i][j] = __builtin_amdgcn_mfma_f32_16x16x32_f16(a_[i], b_[j], acc[i][j], 0, 0, 0);
        __syncthreads();
    }

    // ---- epilogue: two 64-row passes (wr half), sigmoid -> LDS -> NT float4
    #pragma unroll
    for (int half = 0; half < 2; ++half) {
        if (wr == half) {
            #pragma unroll
            for (int i = 0; i < 4; ++i) {
                int rl = i * 16 + (lane >> 4) * 4;
                #pragma unroll
                for (int j = 0; j < 4; ++j) {
                    int cl = wc * 64 + j * 16 + (lane & 15);
                    #pragma unroll
                    for (int r = 0; r < 4; ++r)
                        Ep[(rl + r) * 132 + cl] = 1.f / (1.f + __expf(-acc[i][j][r]));
                }
            }
        }
        __syncthreads();
        #pragma unroll
        for (int it = 0; it < 8; ++it) {
            int idx = it * 256 + tid;
            int row = idx >> 5;
            int c4 = (idx & 31) << 2;
            f32x4 v = *(const f32x4*)&Ep[row * 132 + c4];
            int gc = col0 + c4;
            if (gc < N_ENT)
                __builtin_nontemporal_store(v,
                    (f32x4*)(out + (size_t)(row0 + half * 64 + row) * N_ENT + gc));
        }
        __syncthreads();
    }
}

extern "C" void kernel_launch(void* const* d_in, const int* in_sizes, int n_in,
                              void* d_out, int out_size, void* d_ws, size_t ws_size,
                              hipStream_t stream) {
    const int*   e1    = (const int*)d_in[0];
    const int*   ri    = (const int*)d_in[1];
    const float* emb   = (const float*)d_in[3];
    const float* qw    = (const float*)d_in[4];
    const int*   esrc  = (const int*)d_in[5];
    const int*   edst  = (const int*)d_in[6];
    const float* evalv = (const float*)d_in[7];
    const float* gamma = (const float*)d_in[8];
    const float* beta  = (const float*)d_in[9];
    float* out = (float*)d_out;

    const size_t NODE_F = (size_t)N_NODES * EMB;        // 10,368,000
    _Float16* support_h = (_Float16*)d_ws;              // NODE_F halfs
    _Float16* Xh        = support_h + NODE_F;           // NODE_F halfs
    int*      row_start = (int*)(Xh + NODE_F);          // N_NODES+1
    int*      cnt       = row_start + (N_NODES + 1);    // N_NODES
    int*      cursor    = cnt + N_NODES;                // N_NODES
    int*      bsum      = cursor + N_NODES;             // 41
    int2*     edge_s    = (int2*)(bsum + SCAN_NB + 1);  // N_EDGES int2 (8B-aligned)
    _Float16* hr_h      = (_Float16*)(edge_s + N_EDGES);// 262144 halfs
    _Float16* Hth       = hr_h + 262144;                // 65536 halfs

    hipMemsetAsync(cnt, 0, N_NODES * sizeof(int), stream);
    hist_k<<<(N_EDGES + 255) / 256, 256, 0, stream>>>(esrc, cnt);
    scanham<<<SCAN_NB + 64, 1024, 0, stream>>>(cnt, row_start, bsum, qw, Hth);
    scan_add<<<SCAN_NB, 1024, 0, stream>>>(row_start, cursor, bsum);
    support_place<<<633 + (N_EDGES + 255) / 256, 256, 0, stream>>>(
        emb, Hth, support_h, esrc, edst, evalv, cursor, edge_s);
    spmm_tanh<<<N_NODES / 4, 256, 0, stream>>>(row_start, edge_s, support_h, Xh);
    bn_fused<<<EMB, 256, 0, stream>>>(Xh, e1, ri, gamma, beta, hr_h);
    score_v4<<<dim3(8, 313), 256, 0, stream>>>(hr_h, Xh, out);
}

// Round 14
// 225.167 us; speedup vs baseline: 1.0050x; 1.0050x over previous
//
#include <hip/hip_runtime.h>
#include <math.h>

#define N_ENT 40000
#define N_NODES 40500
#define EMB 256
#define N_EDGES 648000
#define BATCH 1024
#define BN_EPS 1e-5f
#define SCAN_NB 40   // ceil(N_NODES/1024)

typedef __attribute__((ext_vector_type(8))) _Float16 half8;
typedef __attribute__((ext_vector_type(4))) _Float16 half4v;
typedef __attribute__((ext_vector_type(4))) float f32x4;

__device__ __forceinline__ void gl_lds16(const void* g, void* l) {
    __builtin_amdgcn_global_load_lds(
        (const __attribute__((address_space(1))) void*)g,
        (__attribute__((address_space(3))) void*)l, 16, 0, 0);
}

// ---------------------------------------------------------------- CSR: histogram
__global__ void hist_k(const int* __restrict__ src, int* __restrict__ cnt) {
    int e = blockIdx.x * 256 + threadIdx.x;
    if (e < N_EDGES) atomicAdd(&cnt[src[e]], 1);
}

// ---- fused: blocks 0..39 = per-block scan of cnt; blocks 40..103 = hamilton fp16
__global__ __launch_bounds__(1024) void scanham(const int* __restrict__ cnt,
                                                int* __restrict__ row_start,
                                                int* __restrict__ bsum,
                                                const float* __restrict__ qw,
                                                _Float16* __restrict__ Hth) {
    const int t = threadIdx.x;
    if (blockIdx.x < SCAN_NB) {
        __shared__ int wsum[16];
        const int lane = t & 63, wid = t >> 6;
        int idx = blockIdx.x * 1024 + t;
        int v = (idx < N_NODES) ? cnt[idx] : 0;
        int incl = v;
        #pragma unroll
        for (int off = 1; off < 64; off <<= 1) {
            int u = __shfl_up(incl, off);
            if (lane >= off) incl += u;
        }
        if (lane == 63) wsum[wid] = incl;
        __syncthreads();
        if (t < 16) {
            int wv = wsum[t];
            #pragma unroll
            for (int off = 1; off < 16; off <<= 1) {
                int u = __shfl_up(wv, off);
                if (t >= off) wv += u;
            }
            wsum[t] = wv;
        }
        __syncthreads();
        int woff = (wid > 0) ? wsum[wid - 1] : 0;
        incl += woff;
        if (idx < N_NODES) row_start[idx] = incl - v;   // block-local exclusive
        if (t == 1023) bsum[blockIdx.x] = incl;
    } else {
        int idx = (blockIdx.x - SCAN_NB) * 1024 + t;    // 65536
        int o = idx >> 8, i = idx & 255;
        int p = i >> 6, i0 = i & 63;
        int q = o >> 6, o0 = o & 63;
        const int   ctab[16] = {0,1,2,3, 1,0,3,2, 2,3,0,1, 3,2,1,0};
        const float stab[16] = {1.f,1.f,1.f,1.f, -1.f,1.f,1.f,-1.f, -1.f,-1.f,1.f,1.f, -1.f,1.f,-1.f,1.f};
        Hth[idx] = (_Float16)(stab[p*4+q] * qw[i0*EMB + ctab[p*4+q]*64 + o0]);
    }
}

// ---- scan_add: each block redoes the 40-element top scan, adds offset,
// ---- writes row_start + cursor (+ total tail)
__global__ __launch_bounds__(1024) void scan_add(int* __restrict__ row_start,
                                                 int* __restrict__ cursor,
                                                 const int* __restrict__ bsum) {
    __shared__ int off_s, tot_s;
    const int t = threadIdx.x;
    if (t < 64) {
        int v = (t < SCAN_NB) ? bsum[t] : 0;
        int incl = v;
        #pragma unroll
        for (int off = 1; off < 64; off <<= 1) {
            int u = __shfl_up(incl, off);
            if (t >= off) incl += u;
        }
        int off = (blockIdx.x == 0) ? 0 : __shfl(incl, (int)blockIdx.x - 1);
        int tot = __shfl(incl, SCAN_NB - 1);
        if (t == 0) { off_s = off; tot_s = tot; }
    }
    __syncthreads();
    int idx = blockIdx.x * 1024 + t;
    if (idx < N_NODES) {
        int v = row_start[idx] + off_s;
        row_start[idx] = v;
        cursor[idx] = v;
    }
    if (idx == N_NODES) row_start[N_NODES] = tot_s;
}

// ---- fused: blocks 0..632 = support GEMM (fp16 MFMA); blocks 633.. = place_edges
__global__ __launch_bounds__(256) void support_place(const float* __restrict__ emb,
                                                     const _Float16* __restrict__ Hth,
                                                     _Float16* __restrict__ Ch,
                                                     const int* __restrict__ esrc,
                                                     const int* __restrict__ edst,
                                                     const float* __restrict__ evalv,
                                                     int* __restrict__ cursor,
                                                     int2* __restrict__ edge_s) {
    if (blockIdx.x >= 633) {
        int e = (blockIdx.x - 633) * 256 + threadIdx.x;
        if (e < N_EDGES) {
            int pos = atomicAdd(&cursor[esrc[e]], 1);
            edge_s[pos] = make_int2(edst[e], __float_as_int(evalv[e]));
        }
        return;
    }
    const int wid  = threadIdx.x >> 6;
    const int lane = threadIdx.x & 63;
    const int wr = wid >> 1, wc = wid & 1;
    const int row0 = blockIdx.x * 64 + wr * 32;
    const int col0 = wc * 128;
    const int fr = lane & 15;
    const int kg = lane >> 4;
    f32x4 acc[2][8] = {};
    for (int kb = 0; kb < 8; ++kb) {
        const int koff = kb * 32 + kg * 8;
        half8 a[2];
        #pragma unroll
        for (int i = 0; i < 2; ++i) {
            int r = row0 + i * 16 + fr;
            if (r > N_NODES - 1) r = N_NODES - 1;
            const float* src = emb + (size_t)r * EMB + koff;
            float4 va = *(const float4*)(src);
            float4 vb = *(const float4*)(src + 4);
            a[i][0] = (_Float16)va.x; a[i][1] = (_Float16)va.y;
            a[i][2] = (_Float16)va.z; a[i][3] = (_Float16)va.w;
            a[i][4] = (_Float16)vb.x; a[i][5] = (_Float16)vb.y;
            a[i][6] = (_Float16)vb.z; a[i][7] = (_Float16)vb.w;
        }
        half8 b[8];
        #pragma unroll
        for (int j = 0; j < 8; ++j)
            b[j] = *(const half8*)(Hth + (size_t)(col0 + j * 16 + fr) * EMB + koff);
        #pragma unroll
        for (int i = 0; i < 2; ++i)
            #pragma unroll
            for (int j = 0; j < 8; ++j)
                acc[i][j] = __builtin_amdgcn_mfma_f32_16x16x32_f16(a[i], b[j], acc[i][j], 0, 0, 0);
    }
    #pragma unroll
    for (int i = 0; i < 2; ++i) {
        int rbase = row0 + i * 16 + (lane >> 4) * 4;
        #pragma unroll
        for (int j = 0; j < 8; ++j) {
            int c = col0 + j * 16 + (lane & 15);
            #pragma unroll
            for (int r = 0; r < 4; ++r) {
                if (rbase + r < N_NODES)
                    Ch[(size_t)(rbase + r) * EMB + c] = (_Float16)acc[i][j][r];
            }
        }
    }
}

// -------- Xh[row] = tanh( sum val*support_h[dst] )
// v2: 32 lanes x 16 B (half8) per row; two edge streams per wave (even/odd),
// 2-wide unroll -> 4 outstanding dwordx4 gathers; shfl_xor(32) combine.
__global__ __launch_bounds__(256) void spmm_tanh(const int* __restrict__ row_start,
                                                 const int2* __restrict__ edge_s,
                                                 const _Float16* __restrict__ support_h,
                                                 _Float16* __restrict__ Xh) {
    int row = blockIdx.x * 4 + (threadIdx.x >> 6);
    if (row >= N_NODES) return;
    const int lane = threadIdx.x & 63;
    const int sub = lane >> 5;            // 0: even edges, 1: odd edges
    const int fl = lane & 31;             // feature block: fl*8 .. fl*8+7
    const int beg = row_start[row], end = row_start[row + 1];
    float acc[8] = {};
    int i = beg + sub;
    for (; i + 2 < end; i += 4) {         // handles edges i and i+2
        int2 ea = edge_s[i], eb = edge_s[i + 2];
        half8 xa = *(const half8*)(support_h + (size_t)ea.x * EMB + fl * 8);
        half8 xb = *(const half8*)(support_h + (size_t)eb.x * EMB + fl * 8);
        float va = __int_as_float(ea.y), vb = __int_as_float(eb.y);
        #pragma unroll
        for (int j = 0; j < 8; ++j) {
            acc[j] = fmaf(va, (float)xa[j], acc[j]);
            acc[j] = fmaf(vb, (float)xb[j], acc[j]);
        }
    }
    for (; i < end; i += 2) {
        int2 e = edge_s[i];
        half8 x = *(const half8*)(support_h + (size_t)e.x * EMB + fl * 8);
        float v = __int_as_float(e.y);
        #pragma unroll
        for (int j = 0; j < 8; ++j)
            acc[j] = fmaf(v, (float)x[j], acc[j]);
    }
    #pragma unroll
    for (int j = 0; j < 8; ++j)
        acc[j] += __shfl_xor(acc[j], 32);
    if (sub == 0) {
        half8 o;
        #pragma unroll
        for (int j = 0; j < 8; ++j)
            o[j] = (_Float16)tanhf(acc[j]);
        *(half8*)(Xh + (size_t)row * EMB + fl * 8) = o;
    }
}

// ---- fused hr + batchnorm (stats + apply) -> fp16; one block per feature
__global__ __launch_bounds__(256) void bn_fused(const _Float16* __restrict__ Xh,
                                                const int* __restrict__ e1,
                                                const int* __restrict__ ri,
                                                const float* __restrict__ gamma,
                                                const float* __restrict__ beta,
                                                _Float16* __restrict__ hr_h) {
    const int f = blockIdx.x, t = threadIdx.x;
    float v[4];
    float s = 0.f, sq = 0.f;
    #pragma unroll
    for (int k = 0; k < 4; ++k) {
        int b = t + k * 256;
        float h = (float)Xh[(size_t)e1[b] * EMB + f];
        float r = (float)Xh[((size_t)ri[b] + N_ENT) * EMB + f];
        v[k] = h * r;
        s += v[k]; sq += v[k] * v[k];
    }
    #pragma unroll
    for (int off = 32; off > 0; off >>= 1) {
        s  += __shfl_down(s, off);
        sq += __shfl_down(sq, off);
    }
    __shared__ float ss[4], sqs[4], mv[2];
    int w = t >> 6;
    if ((t & 63) == 0) { ss[w] = s; sqs[w] = sq; }
    __syncthreads();
    if (t == 0) {
        s  = ss[0] + ss[1] + ss[2] + ss[3];
        sq = sqs[0] + sqs[1] + sqs[2] + sqs[3];
        float m = s * (1.f / BATCH);
        mv[0] = m;
        mv[1] = sq * (1.f / BATCH) - m * m;
    }
    __syncthreads();
    float mean = mv[0];
    float inv = rsqrtf(mv[1] + BN_EPS) * gamma[f];
    float bet = beta[f];
    #pragma unroll
    for (int k = 0; k < 4; ++k) {
        int b = t + k * 256;
        hr_h[(size_t)b * EMB + f] = (_Float16)((v[k] - mean) * inv + bet);
    }
}

// ------------- out = sigmoid(hr_h @ Xh[:N_ENT]^T), fp16 MFMA LDS GEMM
// v4: block 128(M) x 128(N), BK=32, 4 waves 2x2 (wave 64x64 = 4x4 frags,
// 16 MFMA/step/wave). A LDS [128][32] = bytes 0..8191, B LDS [128][32] =
// bytes 8192..16383 (chunk ch stages at smem + ch*1024, ch = 0..15).
__global__ __launch_bounds__(256) void score_v4(const _Float16* __restrict__ hr_h,
                                                const _Float16* __restrict__ Xh,
                                                float* __restrict__ out) {
    __shared__ char smem[64 * 132 * 4];       // 33.8 KB (K-loop uses first 16 KB)
    _Float16* As = (_Float16*)smem;           // [128][32] bytes 0..8191
    _Float16* Bs = As + 4096;                 // [128][32] bytes 8192..16383
    float* Ep = (float*)smem;                 // [64][132] (epilogue)

    const int tid  = threadIdx.x;
    const int wid  = tid >> 6;
    const int lane = tid & 63;
    const int wr = wid >> 1, wc = wid & 1;
    const int row0 = blockIdx.x * 128;        // M block (8)
    const int col0 = blockIdx.y * 128;        // N block (313)
    const int fr = lane & 15;
    const int kg = lane >> 4;
    const int lrow = lane >> 2;
    const int lchk = (lane & 3) * 8;

    f32x4 acc[4][4] = {};

    for (int kb = 0; kb < 8; ++kb) {
        const int koff = kb * 32;
        #pragma unroll
        for (int c = 0; c < 4; ++c) {
            int ch = wid * 4 + c;                      // 0..15
            if (ch < 8) {
                int lr = ch * 16 + lrow;               // 0..127
                const _Float16* srcA = hr_h + (size_t)(row0 + lr) * EMB + koff + lchk;
                gl_lds16(srcA, smem + ch * 1024);
            } else {
                int br = (ch - 8) * 16 + lrow;         // 0..127
                int gc = col0 + br;
                if (gc > N_ENT - 1) gc = N_ENT - 1;
                const _Float16* srcB = Xh + (size_t)gc * EMB + koff + lchk;
                gl_lds16(srcB, smem + ch * 1024);      // bytes 8192..16383
            }
        }
        __syncthreads();
        half8 a_[4], b_[4];
        #pragma unroll
        for (int i = 0; i < 4; ++i) {
            int r = wr * 64 + i * 16 + fr;
            a_[i] = *(const half8*)&As[r * 32 + kg * 8];
        }
        #pragma unroll
        for (int j = 0; j < 4; ++j) {
            int r = wc * 64 + j * 16 + fr;
            b_[j] = *(const half8*)&Bs[r * 32 + kg * 8];
        }
        #pragma unroll
        for (int i = 0; i < 4; ++i)
            #pragma unroll
            for (int j = 0; j < 4; ++j)
                acc[i][j] = __builtin_amdgcn_mfma_f32_16x16x32_f16(a_[i], b_[j], acc[i][j], 0, 0, 0);
        __syncthreads();
    }

    // ---- epilogue: two 64-row passes (wr half), sigmoid -> LDS -> NT float4
    #pragma unroll
    for (int half = 0; half < 2; ++half) {
        if (wr == half) {
            #pragma unroll
            for (int i = 0; i < 4; ++i) {
                int rl = i * 16 + (lane >> 4) * 4;
                #pragma unroll
                for (int j = 0; j < 4; ++j) {
                    int cl = wc * 64 + j * 16 + (lane & 15);
                    #pragma unroll
                    for (int r = 0; r < 4; ++r)
                        Ep[(rl + r) * 132 + cl] = 1.f / (1.f + __expf(-acc[i][j][r]));
                }
            }
        }
        __syncthreads();
        #pragma unroll
        for (int it = 0; it < 8; ++it) {
            int idx = it * 256 + tid;
            int row = idx >> 5;
            int c4 = (idx & 31) << 2;
            f32x4 v = *(const f32x4*)&Ep[row * 132 + c4];
            int gc = col0 + c4;
            if (gc < N_ENT)
                __builtin_nontemporal_store(v,
                    (f32x4*)(out + (size_t)(row0 + half * 64 + row) * N_ENT + gc));
        }
        __syncthreads();
    }
}

extern "C" void kernel_launch(void* const* d_in, const int* in_sizes, int n_in,
                              void* d_out, int out_size, void* d_ws, size_t ws_size,
                              hipStream_t stream) {
    const int*   e1    = (const int*)d_in[0];
    const int*   ri    = (const int*)d_in[1];
    const float* emb   = (const float*)d_in[3];
    const float* qw    = (const float*)d_in[4];
    const int*   esrc  = (const int*)d_in[5];
    const int*   edst  = (const int*)d_in[6];
    const float* evalv = (const float*)d_in[7];
    const float* gamma = (const float*)d_in[8];
    const float* beta  = (const float*)d_in[9];
    float* out = (float*)d_out;

    const size_t NODE_F = (size_t)N_NODES * EMB;        // 10,368,000
    _Float16* support_h = (_Float16*)d_ws;              // NODE_F halfs
    _Float16* Xh        = support_h + NODE_F;           // NODE_F halfs
    int*      row_start = (int*)(Xh + NODE_F);          // N_NODES+1
    int*      cnt       = row_start + (N_NODES + 1);    // N_NODES
    int*      cursor    = cnt + N_NODES;                // N_NODES
    int*      bsum      = cursor + N_NODES;             // 41
    int2*     edge_s    = (int2*)(bsum + SCAN_NB + 1);  // N_EDGES int2 (8B-aligned)
    _Float16* hr_h      = (_Float16*)(edge_s + N_EDGES);// 262144 halfs
    _Float16* Hth       = hr_h + 262144;                // 65536 halfs

    hipMemsetAsync(cnt, 0, N_NODES * sizeof(int), stream);
    hist_k<<<(N_EDGES + 255) / 256, 256, 0, stream>>>(esrc, cnt);
    scanham<<<SCAN_NB + 64, 1024, 0, stream>>>(cnt, row_start, bsum, qw, Hth);
    scan_add<<<SCAN_NB, 1024, 0, stream>>>(row_start, cursor, bsum);
    support_place<<<633 + (N_EDGES + 255) / 256, 256, 0, stream>>>(
        emb, Hth, support_h, esrc, edst, evalv, cursor, edge_s);
    spmm_tanh<<<N_NODES / 4, 256, 0, stream>>>(row_start, edge_s, support_h, Xh);
    bn_fused<<<EMB, 256, 0, stream>>>(Xh, e1, ri, gamma, beta, hr_h);
    score_v4<<<dim3(8, 313), 256, 0, stream>>>(hr_h, Xh, out);
}